// Round 10
// baseline (599.917 us; speedup 1.0000x reference)
//
#include <hip/hip_runtime.h>
#include <math.h>

#define BB 2
#define VV 4
#define NPTSC 65536
#define HH 256
#define WW 256
#define CCH 128
#define PTS 32            // points per block (verified: halves weight/L2 traffic vs 16)
#define ROWS (VV * PTS)   // 128 rows = 4 views x 32 points
#define LDA 168           // X stride (ushort) — 16B-aligned rows REQUIRED (R3/R4: odd = 3.4x)
#define LDH 136           // Hb stride

typedef __attribute__((ext_vector_type(8))) unsigned short ushort8;
typedef __attribute__((ext_vector_type(4))) unsigned short u16x4;
typedef __attribute__((ext_vector_type(8))) __bf16 bf16x8;
typedef __attribute__((ext_vector_type(4))) float floatx4;

// Static feats buffer (128 MiB); rewritten fully every launch.
__device__ unsigned short g_feats[(size_t)BB * VV * HH * WW * CCH];

__device__ __forceinline__ float b2f(unsigned short u) {
  unsigned int x = ((unsigned int)u) << 16;
  return __builtin_bit_cast(float, x);
}
// Native RTNE convert: v_cvt_pk_bf16_f32 (1 instr) vs 4-instr hand rounding.
__device__ __forceinline__ unsigned short f2b(float f) {
  return __builtin_bit_cast(unsigned short, (__bf16)f);
}

// ---- fused prep+conv (verified R7) ------------------------------------------
// blocks 0..2047: conv, one y-row per block, threads = 128 ch x 2 x-halves.
// blocks 2048..2895: prep (f32 weights -> bf16 [out][in] into d_ws, 434 KB).
__global__ __launch_bounds__(256) void mvct_pc(
    const float* __restrict__ views, const float* __restrict__ conv_w,
    const float* __restrict__ conv_b,
    const float* __restrict__ vw_in, const float* __restrict__ vw1,
    const float* __restrict__ vw2, const float* __restrict__ vw_out,
    const float* __restrict__ gw_in, const float* __restrict__ gw1,
    const float* __restrict__ gw2, unsigned short* __restrict__ wbuf)
{
  if (blockIdx.x < 2048) {
    __shared__ float rows[2][3][132];        // [x-half][tap-row][col]
    const int h = threadIdx.x >> 7;          // x-half 0/1
    const int c = threadIdx.x & 127;         // out channel
    const int bv = blockIdx.x >> 8;          // 8 bv x 256 y-rows
    const int y = blockIdx.x & 255;
    const int xb = h * 128;

    float w[9];
#pragma unroll
    for (int j = 0; j < 9; ++j) w[j] = conv_w[c * 9 + j];
    const float bias = conv_b[c];

    const float* img = views + (size_t)bv * HH * WW;
#pragma unroll
    for (int r = 0; r < 3; ++r) {
      int yy = y - 1 + r;
      for (int xcol = c; xcol < 130; xcol += 128) {
        int xx = xb - 1 + xcol;
        float v = 0.f;
        if (yy >= 0 && yy < HH && xx >= 0 && xx < WW) v = img[yy * WW + xx];
        rows[h][r][xcol] = v;
      }
    }
    __syncthreads();

    unsigned short* orow =
        g_feats + ((size_t)((bv * HH + y) * WW + xb)) * CCH + c;
    float a0 = rows[h][0][0], a1 = rows[h][1][0], a2 = rows[h][2][0];
    float b0 = rows[h][0][1], b1 = rows[h][1][1], b2 = rows[h][2][1];
#pragma unroll 8
    for (int x = 0; x < 128; ++x) {
      float c0 = rows[h][0][x + 2];
      float c1 = rows[h][1][x + 2];
      float c2 = rows[h][2][x + 2];
      float acc = bias
        + a0 * w[0] + b0 * w[1] + c0 * w[2]
        + a1 * w[3] + b1 * w[4] + c1 * w[5]
        + a2 * w[6] + b2 * w[7] + c2 * w[8];
      acc = fmaxf(acc, 0.f);
      orow[(size_t)x * CCH] = f2b(acc);
      a0 = b0; a1 = b1; a2 = b2;
      b0 = c0; b1 = c1; b2 = c2;
    }
  } else {
    // ---- prep ----
    int tid = (blockIdx.x - 2048) * 256 + threadIdx.x;
    if (tid >= 217088) return;
    float val;
    if (tid < 20480) {
      int n = tid / 160, k = tid - n * 160;
      val = (k < 137) ? vw_in[k * 128 + n] : 0.f;
    } else {
      int t = tid - 20480;
      const float* src;
      if (t < 49152) { src = vw1; }
      else if (t < 98304) { t -= 49152; src = vw2; }
      else if (t < 114688) { t -= 98304; src = vw_out; }
      else if (t < 131072) { t -= 114688; src = gw_in; }
      else if (t < 163840) { t -= 131072; src = gw1; }
      else { t -= 163840; src = gw2; }
      int i = t >> 14; int r = t & 16383; int n = r >> 7; int k = r & 127;
      val = src[i * 16384 + k * 128 + n];
    }
    wbuf[tid] = f2b(val);
  }
}

// ---- weight register set: 2 ftiles x 4 k-chunks (K=128) + biases -----------
struct WReg {
  ushort8 a[2][4];
  floatx4 bs[2];
};

__device__ __forceinline__ WReg wload(const unsigned short* __restrict__ Wt,
                                      const float* __restrict__ bias,
                                      int lane, int ftBase) {
  WReg w;
  const int col = lane & 15, quad = lane >> 4;
#pragma unroll
  for (int ftl = 0; ftl < 2; ++ftl) {
    const int ft = ftBase + ftl;
#pragma unroll
    for (int kk = 0; kk < 4; ++kk)
      w.a[ftl][kk] = *(const ushort8*)(Wt + (ft * 16 + col) * 128 + kk * 32 + quad * 8);
    w.bs[ftl] = *(const floatx4*)(bias + ft * 16 + quad * 4);
  }
  return w;
}

// ---- MFMA MLP compute (K=128), weights in registers ------------------------
// A=weights (m=out-feat), B=acts (n=row). D[m=ft*16+quad*4+r][n=rowBase+ptt*16+col].
// acc initialized from bias (layout-exact; verified R8/R9 numerically).
// MODE 0: relu+store; MODE 1: relu+residual+store; MODE 2: accumulate racc
// (slot (ptt&1): rows rowBase+ptt*16+col -> view rh*2+(ptt>>1), point (ptt&1)*16+col;
//  slot merges 2 views of the same point-half; bias enters 2x/half, /4 at mean).
template<int MODE, int NPT>
__device__ __forceinline__ void mlp_c(
    const unsigned short* Act, int lda, const WReg& w,
    const unsigned short* Res, int ldr,
    unsigned short* Dst, int ldd,
    float* racc, int lane, int ftBase, int rowBase)
{
  const int col = lane & 15, quad = lane >> 4;
  auto body = [&](int ptt) {
    const int row = rowBase + ptt * 16 + col;
    ushort8 bfr[4];
#pragma unroll
    for (int kk = 0; kk < 4; ++kk)
      bfr[kk] = *(const ushort8*)(Act + row * lda + kk * 32 + quad * 8);
#pragma unroll
    for (int ftl = 0; ftl < 2; ++ftl) {
      const int ft = ftBase + ftl;
      floatx4 acc = w.bs[ftl];
#pragma unroll
      for (int kk = 0; kk < 4; ++kk)
        acc = __builtin_amdgcn_mfma_f32_16x16x32_bf16(
            __builtin_bit_cast(bf16x8, w.a[ftl][kk]),
            __builtin_bit_cast(bf16x8, bfr[kk]), acc, 0, 0, 0);
      if constexpr (MODE == 2) {
#pragma unroll
        for (int r = 0; r < 4; ++r)
          racc[(ptt & 1) * 8 + ftl * 4 + r] += acc[r];
      } else {
        u16x4 rv;
        if constexpr (MODE == 1)
          rv = *(const u16x4*)(Res + row * ldr + ft * 16 + quad * 4);
        u16x4 o;
#pragma unroll
        for (int r = 0; r < 4; ++r) {
          float v = acc[r];
          if constexpr (MODE == 1) v += b2f(rv[r]);
          v = fmaxf(v, 0.f);
          o[r] = f2b(v);
        }
        *(u16x4*)(Dst + row * ldd + ft * 16 + quad * 4) = o;
      }
    }
  };
  if constexpr (MODE == 2) {
#pragma unroll
    for (int ptt = 0; ptt < NPT; ++ptt) body(ptt);
  } else {
#pragma unroll 2
    for (int ptt = 0; ptt < NPT; ++ptt) body(ptt);
  }
  __syncthreads();
}

// ---- first layer (K=160), self-loading weights -----------------------------
__device__ __forceinline__ void mlp_first(
    const unsigned short* Act, int lda,
    const unsigned short* __restrict__ Wt, const float* __restrict__ bias,
    unsigned short* Dst, int ldd, int lane, int ftBase, int rowBase)
{
  const int col = lane & 15, quad = lane >> 4;
  ushort8 afr[2][5];
  floatx4 bs4[2];
#pragma unroll
  for (int ftl = 0; ftl < 2; ++ftl) {
    const int ft = ftBase + ftl;
#pragma unroll
    for (int kk = 0; kk < 5; ++kk)
      afr[ftl][kk] = *(const ushort8*)(Wt + (ft * 16 + col) * 160 + kk * 32 + quad * 8);
    bs4[ftl] = *(const floatx4*)(bias + ft * 16 + quad * 4);
  }
#pragma unroll 2
  for (int ptt = 0; ptt < 4; ++ptt) {
    const int row = rowBase + ptt * 16 + col;
    ushort8 bfr[5];
#pragma unroll
    for (int kk = 0; kk < 5; ++kk)
      bfr[kk] = *(const ushort8*)(Act + row * lda + kk * 32 + quad * 8);
#pragma unroll
    for (int ftl = 0; ftl < 2; ++ftl) {
      const int ft = ftBase + ftl;
      floatx4 acc = bs4[ftl];
#pragma unroll
      for (int kk = 0; kk < 5; ++kk)
        acc = __builtin_amdgcn_mfma_f32_16x16x32_bf16(
            __builtin_bit_cast(bf16x8, afr[ftl][kk]),
            __builtin_bit_cast(bf16x8, bfr[kk]), acc, 0, 0, 0);
      u16x4 o;
#pragma unroll
      for (int r = 0; r < 4; ++r)
        o[r] = f2b(fmaxf(acc[r], 0.f));
      *(u16x4*)(Dst + row * ldd + ft * 16 + quad * 4) = o;
    }
  }
  __syncthreads();
}

// ---- main: 8 waves (rh x ftile-pair) + dual-WReg prefetch pipeline ---------
// 4096 blocks x 512 thr; wave w: rh=w>>2 owns rows rh*64.., fp=w&3 owns
// ftiles 2fp,2fp+1. ALL verified ingredients together (untested combination):
//  - PTS=32 (R1: halved weight traffic)      - dual-WReg2 prefetch (R1 vs R8)
//  - aligned strides 168/136 (R3/R4 lesson)  - (512,2): VGPR 88 no-spill (R4)
// LDS 77.8 KB -> 2 blocks/CU x 8 waves = 16 waves/CU (4/SIMD — 2x R7's pool).
__global__ __launch_bounds__(512, 2) void mvct_main(
    const float* __restrict__ angles, const int* __restrict__ idx,
    const unsigned short* __restrict__ wbuf,
    const float* __restrict__ vb_in, const float* __restrict__ vb1,
    const float* __restrict__ vb2, const float* __restrict__ vb_out,
    const float* __restrict__ gb_in, const float* __restrict__ gb1,
    const float* __restrict__ gb2, const float* __restrict__ gw_out,
    const float* __restrict__ gb_out,
    float* __restrict__ out)
{
  __shared__ __align__(16) unsigned short X[ROWS][LDA];
  __shared__ __align__(16) unsigned short Hb[ROWS][LDH];
  const int tid = threadIdx.x;
  const int lane = tid & 63;
  const int wav = tid >> 6;                    // 0..7
  const int rh = wav >> 2;                     // row half: rows rh*64..rh*64+63
  const int ftBase = (wav & 3) * 2;            // ftiles 2fp, 2fp+1
  const int rowBase = rh * 64;
  const int b = blockIdx.x >> 11;              // 2048 groups per batch
  const int pts0 = (blockIdx.x & 2047) * PTS;

  const unsigned short* w_in_t   = wbuf;
  const unsigned short* vw1_t    = wbuf + 20480;
  const unsigned short* vw2_t    = wbuf + 69632;
  const unsigned short* vw_out_t = wbuf + 118784;
  const unsigned short* gw_in_t  = wbuf + 135168;
  const unsigned short* gw1_t    = wbuf + 151552;
  const unsigned short* gw2_t    = wbuf + 184320;

  const float inv = 2.0f / 127.0f;
  const int col = lane & 15, quad = lane >> 4;

  // PE into X rows 0..127 cols 128..159 (per-row point p = row&31)
  if (tid < ROWS) {
    int p = tid & (PTS - 1);
    int id = idx[pts0 + p];
    int iz = (id >> 14) & 127, iy = (id >> 7) & 127, ix = id & 127;
    float x = ix * inv - 1.f, y = iy * inv - 1.f, z = iz * inv - 1.f;
    const float PI = 3.14159265358979323846f;
    float pe[9] = {z, y, x, sinf(PI * z), sinf(PI * y), sinf(PI * x),
                   cosf(PI * z), cosf(PI * y), cosf(PI * x)};
#pragma unroll
    for (int j = 0; j < 9; ++j) X[tid][128 + j] = f2b(pe[j]);
    for (int j = 137; j < 160; ++j) X[tid][j] = 0;
  }

  // sampling: 512 threads = one (point, ch-group) each; v-loop gathers overlap
  {
    const int cg = tid & 15;
    const int p = (tid >> 4) & 31;
    const int id = idx[pts0 + p];
    const int iz = (id >> 14) & 127, iy = (id >> 7) & 127, ix = id & 127;
    const float x = ix * inv - 1.f, y = iy * inv - 1.f, z = iz * inv - 1.f;
#pragma unroll
    for (int v = 0; v < VV; ++v) {
      const int bv = b * VV + v;
      const float ang = angles[bv];
      const float ct = cosf(ang), st = sinf(ang);
      float u = x * ct - y * st;
      float px = (u + 1.f) * 127.5f, py = (z + 1.f) * 127.5f;
      px = fminf(fmaxf(px, 0.f), 255.f);
      py = fminf(fmaxf(py, 0.f), 255.f);
      int x0 = min((int)px, 254), y0 = min((int)py, 254);
      float wx = px - (float)x0, wy = py - (float)y0;
      const unsigned short* bp =
          g_feats + ((size_t)((bv * HH + y0) * WW + x0)) * CCH + cg * 8;
      ushort8 q00 = *(const ushort8*)bp;
      ushort8 q01 = *(const ushort8*)(bp + CCH);
      ushort8 q10 = *(const ushort8*)(bp + WW * CCH);
      ushort8 q11 = *(const ushort8*)(bp + WW * CCH + CCH);
      float w00 = (1.f - wx) * (1.f - wy), w01 = wx * (1.f - wy);
      float w10 = (1.f - wx) * wy, w11 = wx * wy;
      ushort8 o;
#pragma unroll
      for (int j = 0; j < 8; ++j) {
        float f = w00 * b2f(q00[j]) + w01 * b2f(q01[j]) +
                  w10 * b2f(q10[j]) + w11 * b2f(q11[j]);
        o[j] = f2b(f);
      }
      *(ushort8*)&X[v * PTS + p][cg * 8] = o;
    }
  }
  __syncthreads();

  float racc[16];
#pragma unroll
  for (int i = 0; i < 16; ++i) racc[i] = 0.f;

  // Explicit software pipeline: wload(L+1) issues right after the previous
  // barrier and overlaps layer L's MFMA. By-value WReg, no pointers -> no spill.
  WReg wA = wload(vw1_t, vb1, lane, ftBase);                       // L1
  mlp_first(&X[0][0], LDA, w_in_t, vb_in, &Hb[0][0], LDH, lane, ftBase, rowBase);
  WReg wB = wload(vw2_t, vb2, lane, ftBase);                       // L2
  mlp_c<0, 4>(&Hb[0][0], LDH, wA, nullptr, 0, &X[0][0], LDA, nullptr,
              lane, ftBase, rowBase);                               // L1
  wA = wload(vw1_t + 16384, vb1 + 128, lane, ftBase);              // L3
  mlp_c<1, 4>(&X[0][0], LDA, wB, &Hb[0][0], LDH, &Hb[0][0], LDH, nullptr,
              lane, ftBase, rowBase);                               // L2
  wB = wload(vw2_t + 16384, vb2 + 128, lane, ftBase);              // L4
  mlp_c<0, 4>(&Hb[0][0], LDH, wA, nullptr, 0, &X[0][0], LDA, nullptr,
              lane, ftBase, rowBase);                               // L3
  wA = wload(vw1_t + 32768, vb1 + 256, lane, ftBase);              // L5
  mlp_c<1, 4>(&X[0][0], LDA, wB, &Hb[0][0], LDH, &Hb[0][0], LDH, nullptr,
              lane, ftBase, rowBase);                               // L4
  wB = wload(vw2_t + 32768, vb2 + 256, lane, ftBase);              // L6
  mlp_c<0, 4>(&Hb[0][0], LDH, wA, nullptr, 0, &X[0][0], LDA, nullptr,
              lane, ftBase, rowBase);                               // L5
  wA = wload(vw_out_t, vb_out, lane, ftBase);                      // L7
  mlp_c<1, 4>(&X[0][0], LDA, wB, &Hb[0][0], LDH, &Hb[0][0], LDH, nullptr,
              lane, ftBase, rowBase);                               // L6
  wB = wload(gw_in_t, gb_in, lane, ftBase);                        // G0
  mlp_c<2, 4>(&Hb[0][0], LDH, wA, nullptr, 0, nullptr, 0, racc,
              lane, ftBase, rowBase);                               // L7 acc

  // mean over views: rh=1 (views 2,3) dumps f32 partials to scratch (overlaid
  // on dead X rows 32+); rh=0 (views 0,1) combines -> X rows 0..31.
  wA = wload(gw1_t, gb1, lane, ftBase);                            // G1 (overlap)
  float* scr = (float*)((char*)&X[0][0] + 32 * LDA * 2);  // [32][132] f32
  if (rh == 1) {
#pragma unroll
    for (int ph = 0; ph < 2; ++ph)
#pragma unroll
      for (int ftl = 0; ftl < 2; ++ftl) {
        floatx4 v4;
#pragma unroll
        for (int r = 0; r < 4; ++r) v4[r] = racc[ph * 8 + ftl * 4 + r];
        *(floatx4*)&scr[(ph * 16 + col) * 132 + (ftBase + ftl) * 16 + quad * 4] = v4;
      }
  }
  __syncthreads();
  if (rh == 0) {
#pragma unroll
    for (int ph = 0; ph < 2; ++ph)
#pragma unroll
      for (int ftl = 0; ftl < 2; ++ftl) {
        floatx4 pv = *(const floatx4*)&scr[(ph * 16 + col) * 132 +
                                           (ftBase + ftl) * 16 + quad * 4];
        u16x4 o;
#pragma unroll
        for (int r = 0; r < 4; ++r)
          o[r] = f2b((racc[ph * 8 + ftl * 4 + r] + pv[r]) * 0.25f);
        *(u16x4*)(&X[ph * 16 + col][(ftBase + ftl) * 16 + quad * 4]) = o;
      }
  }
  __syncthreads();

  // G layers: 32 rows total; wave row-half rh owns rows rh*16..rh*16+15.
  const int gBase = rh * 16;
  mlp_c<0, 1>(&X[0][0], LDA, wB, nullptr, 0, &Hb[0][0], LDH, nullptr,
              lane, ftBase, gBase);                                 // G0
  wB = wload(gw2_t, gb2, lane, ftBase);                            // G2
  mlp_c<0, 1>(&Hb[0][0], LDH, wA, nullptr, 0, &X[0][0], LDA, nullptr,
              lane, ftBase, gBase);                                 // G1
  wA = wload(gw1_t + 16384, gb1 + 128, lane, ftBase);              // G3
  mlp_c<1, 1>(&X[0][0], LDA, wB, &Hb[0][0], LDH, &Hb[0][0], LDH, nullptr,
              lane, ftBase, gBase);                                 // G2
  wB = wload(gw2_t + 16384, gb2 + 128, lane, ftBase);              // G4
  mlp_c<0, 1>(&Hb[0][0], LDH, wA, nullptr, 0, &X[0][0], LDA, nullptr,
              lane, ftBase, gBase);                                 // G3
  mlp_c<1, 1>(&X[0][0], LDA, wB, &Hb[0][0], LDH, &Hb[0][0], LDH, nullptr,
              lane, ftBase, gBase);                                 // G4

  // out = h @ gw_out + gb_out; 32 points, 4 lanes/point, waves 0-1
  if (tid < 128) {
    const int p = (tid & 15) + ((tid >> 6) << 4);  // wave0: 0..15, wave1: 16..31
    const int q4 = (tid >> 4) & 3;
    float s = 0.f;
    const unsigned short* hr = &Hb[p][q4 * 32];
    const float* wo = gw_out + q4 * 32;
#pragma unroll
    for (int c = 0; c < 32; ++c)
      s += b2f(hr[c]) * wo[c];
    s += __shfl_xor(s, 16, 64);
    s += __shfl_xor(s, 32, 64);
    if (q4 == 0)
      out[(size_t)b * NPTSC + pts0 + p] = s + gb_out[0];
  }
}

extern "C" void kernel_launch(void* const* d_in, const int* in_sizes, int n_in,
                              void* d_out, int out_size, void* d_ws, size_t ws_size,
                              hipStream_t stream) {
  const float* views  = (const float*)d_in[0];
  const float* angles = (const float*)d_in[1];
  const int*   idx    = (const int*)d_in[2];
  const float* conv_w = (const float*)d_in[3];
  const float* conv_b = (const float*)d_in[4];
  const float* vw_in  = (const float*)d_in[5];
  const float* vb_in  = (const float*)d_in[6];
  const float* vw1    = (const float*)d_in[7];
  const float* vb1    = (const float*)d_in[8];
  const float* vw2    = (const float*)d_in[9];
  const float* vb2    = (const float*)d_in[10];
  const float* vw_out = (const float*)d_in[11];
  const float* vb_out = (const float*)d_in[12];
  const float* gw_in  = (const float*)d_in[13];
  const float* gb_in  = (const float*)d_in[14];
  const float* gw1    = (const float*)d_in[15];
  const float* gb1    = (const float*)d_in[16];
  const float* gw2    = (const float*)d_in[17];
  const float* gb2    = (const float*)d_in[18];
  const float* gw_out = (const float*)d_in[19];
  const float* gb_out = (const float*)d_in[20];

  unsigned short* wbuf = (unsigned short*)d_ws;  // 434 KB

  // fused prep+conv: 2048 conv blocks + 848 prep blocks
  hipLaunchKernelGGL(mvct_pc, dim3(2896), dim3(256), 0, stream,
                     views, conv_w, conv_b,
                     vw_in, vw1, vw2, vw_out, gw_in, gw1, gw2, wbuf);
  hipLaunchKernelGGL(mvct_main, dim3(BB * (NPTSC / PTS)), dim3(512), 0, stream,
                     angles, idx, wbuf, vb_in, vb1, vb2, vb_out,
                     gb_in, gb1, gb2, gw_out, gb_out,
                     (float*)d_out);
}

// Round 11
// 393.747 us; speedup vs baseline: 1.5236x; 1.5236x over previous
//
#include <hip/hip_runtime.h>
#include <math.h>

#define BB 2
#define VV 4
#define NPTSC 65536
#define HH 256
#define WW 256
#define CCH 128
#define PTS 32            // points per block
#define ROWS (VV * PTS)   // 128 rows = 4 views x 32 points

typedef __attribute__((ext_vector_type(8))) unsigned short ushort8;
typedef __attribute__((ext_vector_type(4))) unsigned short u16x4;
typedef __attribute__((ext_vector_type(8))) __bf16 bf16x8;
typedef __attribute__((ext_vector_type(4))) float floatx4;

// Static feats buffer (128 MiB); rewritten fully every launch.
__device__ unsigned short g_feats[(size_t)BB * VV * HH * WW * CCH];

__device__ __forceinline__ float b2f(unsigned short u) {
  unsigned int x = ((unsigned int)u) << 16;
  return __builtin_bit_cast(float, x);
}
// Native RTNE convert: v_cvt_pk_bf16_f32 (1 instr) vs 4-instr hand rounding.
__device__ __forceinline__ unsigned short f2b(float f) {
  return __builtin_bit_cast(unsigned short, (__bf16)f);
}

// ---- fused prep+conv (verified R7) ------------------------------------------
// blocks 0..2047: conv, one y-row per block, threads = 128 ch x 2 x-halves.
//   Sliding-window taps in registers: 3 LDS reads/px instead of 9.
// blocks 2048..2895: prep (f32 weights -> bf16 [out][in] into d_ws, 434 KB).
__global__ __launch_bounds__(256) void mvct_pc(
    const float* __restrict__ views, const float* __restrict__ conv_w,
    const float* __restrict__ conv_b,
    const float* __restrict__ vw_in, const float* __restrict__ vw1,
    const float* __restrict__ vw2, const float* __restrict__ vw_out,
    const float* __restrict__ gw_in, const float* __restrict__ gw1,
    const float* __restrict__ gw2, unsigned short* __restrict__ wbuf)
{
  if (blockIdx.x < 2048) {
    __shared__ float rows[2][3][132];        // [x-half][tap-row][col]
    const int h = threadIdx.x >> 7;          // x-half 0/1
    const int c = threadIdx.x & 127;         // out channel
    const int bv = blockIdx.x >> 8;          // 8 bv x 256 y-rows
    const int y = blockIdx.x & 255;
    const int xb = h * 128;

    float w[9];
#pragma unroll
    for (int j = 0; j < 9; ++j) w[j] = conv_w[c * 9 + j];
    const float bias = conv_b[c];

    const float* img = views + (size_t)bv * HH * WW;
#pragma unroll
    for (int r = 0; r < 3; ++r) {
      int yy = y - 1 + r;
      for (int xcol = c; xcol < 130; xcol += 128) {
        int xx = xb - 1 + xcol;
        float v = 0.f;
        if (yy >= 0 && yy < HH && xx >= 0 && xx < WW) v = img[yy * WW + xx];
        rows[h][r][xcol] = v;
      }
    }
    __syncthreads();

    unsigned short* orow =
        g_feats + ((size_t)((bv * HH + y) * WW + xb)) * CCH + c;
    float a0 = rows[h][0][0], a1 = rows[h][1][0], a2 = rows[h][2][0];
    float b0 = rows[h][0][1], b1 = rows[h][1][1], b2 = rows[h][2][1];
#pragma unroll 8
    for (int x = 0; x < 128; ++x) {
      float c0 = rows[h][0][x + 2];
      float c1 = rows[h][1][x + 2];
      float c2 = rows[h][2][x + 2];
      float acc = bias
        + a0 * w[0] + b0 * w[1] + c0 * w[2]
        + a1 * w[3] + b1 * w[4] + c1 * w[5]
        + a2 * w[6] + b2 * w[7] + c2 * w[8];
      acc = fmaxf(acc, 0.f);
      orow[(size_t)x * CCH] = f2b(acc);
      a0 = b0; a1 = b1; a2 = b2;
      b0 = c0; b1 = c1; b2 = c2;
    }
  } else {
    // ---- prep ----
    int tid = (blockIdx.x - 2048) * 256 + threadIdx.x;
    if (tid >= 217088) return;
    float val;
    if (tid < 20480) {
      int n = tid / 160, k = tid - n * 160;
      val = (k < 137) ? vw_in[k * 128 + n] : 0.f;
    } else {
      int t = tid - 20480;
      const float* src;
      if (t < 49152) { src = vw1; }
      else if (t < 98304) { t -= 49152; src = vw2; }
      else if (t < 114688) { t -= 98304; src = vw_out; }
      else if (t < 131072) { t -= 114688; src = gw_in; }
      else if (t < 163840) { t -= 131072; src = gw1; }
      else { t -= 163840; src = gw2; }
      int i = t >> 14; int r = t & 16383; int n = r >> 7; int k = r & 127;
      val = src[i * 16384 + k * 128 + n];
    }
    wbuf[tid] = f2b(val);
  }
}

// ---- weight register set: 2 ftiles x 4 k-chunks (K=128) + biases -----------
struct WReg {
  ushort8 a[2][4];
  floatx4 bs[2];
};

__device__ __forceinline__ WReg wload(const unsigned short* __restrict__ Wt,
                                      const float* __restrict__ bias,
                                      int lane, int ftBase) {
  WReg w;
  const int col = lane & 15, quad = lane >> 4;
#pragma unroll
  for (int ftl = 0; ftl < 2; ++ftl) {
    const int ft = ftBase + ftl;
#pragma unroll
    for (int kk = 0; kk < 4; ++kk)
      w.a[ftl][kk] = *(const ushort8*)(Wt + (ft * 16 + col) * 128 + kk * 32 + quad * 8);
    w.bs[ftl] = *(const floatx4*)(bias + ft * 16 + quad * 4);
  }
  return w;
}

// ---- MFMA MLP compute (K=128), weights in registers ------------------------
// A=weights (m=out-feat), B=acts (n=row). D[m=ft*16+quad*4+r][n=ptt*16+col].
// acc initialized from bias (layout-exact: acc[r] <-> feat quad*4+r; verified
// bit-identical in R8/R9/R10 benches). MODE 0: relu+store; MODE 1:
// relu+residual+store; MODE 2: accumulate racc (bias enters once per ptt =
// 4x per point-slot, /4 at the view-mean = bias — matches reference).
// MODE 0/1 ptt loop unroll-2 (I-cache); MODE 2 fully unrolled (static racc idx).
template<int MODE, int NPT>
__device__ __forceinline__ void mlp_c(
    const unsigned short* Act, int lda, const WReg& w,
    const unsigned short* Res, int ldr,
    unsigned short* Dst, int ldd,
    float* racc, int lane, int ftBase)
{
  const int col = lane & 15, quad = lane >> 4;
  auto body = [&](int ptt) {
    ushort8 bfr[4];
#pragma unroll
    for (int kk = 0; kk < 4; ++kk)
      bfr[kk] = *(const ushort8*)(Act + (ptt * 16 + col) * lda + kk * 32 + quad * 8);
#pragma unroll
    for (int ftl = 0; ftl < 2; ++ftl) {
      const int ft = ftBase + ftl;
      floatx4 acc = w.bs[ftl];
#pragma unroll
      for (int kk = 0; kk < 4; ++kk)
        acc = __builtin_amdgcn_mfma_f32_16x16x32_bf16(
            __builtin_bit_cast(bf16x8, w.a[ftl][kk]),
            __builtin_bit_cast(bf16x8, bfr[kk]), acc, 0, 0, 0);
      const int row = ptt * 16 + col;
      if constexpr (MODE == 2) {
#pragma unroll
        for (int r = 0; r < 4; ++r)
          racc[(ptt & 1) * 8 + ftl * 4 + r] += acc[r];
      } else {
        u16x4 rv;
        if constexpr (MODE == 1)
          rv = *(const u16x4*)(Res + row * ldr + ft * 16 + quad * 4);
        u16x4 o;
#pragma unroll
        for (int r = 0; r < 4; ++r) {
          float v = acc[r];
          if constexpr (MODE == 1) v += b2f(rv[r]);
          v = fmaxf(v, 0.f);
          o[r] = f2b(v);
        }
        *(u16x4*)(Dst + row * ldd + ft * 16 + quad * 4) = o;
      }
    }
  };
  if constexpr (MODE == 2) {
#pragma unroll
    for (int ptt = 0; ptt < NPT; ++ptt) body(ptt);
  } else {
#pragma unroll 2
    for (int ptt = 0; ptt < NPT; ++ptt) body(ptt);
  }
  __syncthreads();
}

// ---- first layer (K=160), self-loading weights -----------------------------
__device__ __forceinline__ void mlp_first(
    const unsigned short* Act, int lda,
    const unsigned short* __restrict__ Wt, const float* __restrict__ bias,
    unsigned short* Dst, int ldd, int lane, int ftBase)
{
  const int col = lane & 15, quad = lane >> 4;
  ushort8 afr[2][5];
  floatx4 bs4[2];
#pragma unroll
  for (int ftl = 0; ftl < 2; ++ftl) {
    const int ft = ftBase + ftl;
#pragma unroll
    for (int kk = 0; kk < 5; ++kk)
      afr[ftl][kk] = *(const ushort8*)(Wt + (ft * 16 + col) * 160 + kk * 32 + quad * 8);
    bs4[ftl] = *(const floatx4*)(bias + ft * 16 + quad * 4);
  }
#pragma unroll 2
  for (int ptt = 0; ptt < (ROWS / 16); ++ptt) {
    ushort8 bfr[5];
#pragma unroll
    for (int kk = 0; kk < 5; ++kk)
      bfr[kk] = *(const ushort8*)(Act + (ptt * 16 + col) * lda + kk * 32 + quad * 8);
#pragma unroll
    for (int ftl = 0; ftl < 2; ++ftl) {
      const int ft = ftBase + ftl;
      floatx4 acc = bs4[ftl];
#pragma unroll
      for (int kk = 0; kk < 5; ++kk)
        acc = __builtin_amdgcn_mfma_f32_16x16x32_bf16(
            __builtin_bit_cast(bf16x8, afr[ftl][kk]),
            __builtin_bit_cast(bf16x8, bfr[kk]), acc, 0, 0, 0);
      const int row = ptt * 16 + col;
      u16x4 o;
#pragma unroll
      for (int r = 0; r < 4; ++r)
        o[r] = f2b(fmaxf(acc[r], 0.f));
      *(u16x4*)(Dst + row * ldd + ft * 16 + quad * 4) = o;
    }
  }
  __syncthreads();
}

// ---- main: 4-view-batched + explicit weight-prefetch pipeline --------------
// 4096 blocks x 256 thr (4 waves), 32 pts/block; rows = (view,point), 128 rows.
// VERIFIED JOINT OPTIMUM (R7=311us main; R8/R9/R10 all measured worse):
//  - dual-WReg prefetch state ~160 total regs (VGPR+acc, unified file) ->
//    2 waves/SIMD register class. 4-wave blocks x 2 blocks/CU = exactly 2/SIMD
//    AND exactly 2x77.8KB LDS: both resources saturate simultaneously.
//  - 8-wave blocks (R10): one block/CU only -> no desync -> 513us.
//  - single-WReg for 4 waves/SIMD (R8): exposed per-layer weight-load -> 490us.
//  - PTS=16 (R9): doubles weight/L2 traffic + WReg4 spill -> 488us.
//  - LDS row strides MUST stay 16B-aligned (168/136): odd-element strides
//    misalign b128/b64 DS ops -> 3.4x slowdown (R3/R4).
__global__ __launch_bounds__(256, 2) void mvct_main(
    const float* __restrict__ angles, const int* __restrict__ idx,
    const unsigned short* __restrict__ wbuf,
    const float* __restrict__ vb_in, const float* __restrict__ vb1,
    const float* __restrict__ vb2, const float* __restrict__ vb_out,
    const float* __restrict__ gb_in, const float* __restrict__ gb1,
    const float* __restrict__ gb2, const float* __restrict__ gw_out,
    const float* __restrict__ gb_out,
    float* __restrict__ out)
{
  __shared__ __align__(16) unsigned short X[ROWS][168];
  __shared__ __align__(16) unsigned short Hb[ROWS][136];
  const int tid = threadIdx.x;
  const int lane = tid & 63;
  const int ftBase = (tid >> 6) * 2;           // wave w: ftiles 2w, 2w+1
  const int b = blockIdx.x >> 11;              // 2048 groups per batch
  const int pts0 = (blockIdx.x & 2047) * PTS;

  const unsigned short* w_in_t   = wbuf;
  const unsigned short* vw1_t    = wbuf + 20480;
  const unsigned short* vw2_t    = wbuf + 69632;
  const unsigned short* vw_out_t = wbuf + 118784;
  const unsigned short* gw_in_t  = wbuf + 135168;
  const unsigned short* gw1_t    = wbuf + 151552;
  const unsigned short* gw2_t    = wbuf + 184320;

  const float inv = 2.0f / 127.0f;
  const int col = lane & 15, quad = lane >> 4;

  // PE into X rows 0..127 cols 128..159 (per-row point p = row&31)
  if (tid < ROWS) {
    int p = tid & (PTS - 1);
    int id = idx[pts0 + p];
    int iz = (id >> 14) & 127, iy = (id >> 7) & 127, ix = id & 127;
    float x = ix * inv - 1.f, y = iy * inv - 1.f, z = iz * inv - 1.f;
    const float PI = 3.14159265358979323846f;
    float pe[9] = {z, y, x, sinf(PI * z), sinf(PI * y), sinf(PI * x),
                   cosf(PI * z), cosf(PI * y), cosf(PI * x)};
#pragma unroll
    for (int j = 0; j < 9; ++j) X[tid][128 + j] = f2b(pe[j]);
    for (int j = 137; j < 160; ++j) X[tid][j] = 0;
  }

  // sampling: unrolled so the 8 (view, point-half) independent gathers overlap
#pragma unroll
  for (int v = 0; v < VV; ++v) {
    const int bv = b * VV + v;
    const float ang = angles[bv];
    const float ct = cosf(ang), st = sinf(ang);
    const int cg = tid & 15;
#pragma unroll
    for (int ph = 0; ph < 2; ++ph) {
      const int p = ((tid >> 4) & 15) + ph * 16;
      int id = idx[pts0 + p];
      int iz = (id >> 14) & 127, iy = (id >> 7) & 127, ix = id & 127;
      float x = ix * inv - 1.f, y = iy * inv - 1.f, z = iz * inv - 1.f;
      float u = x * ct - y * st;
      float px = (u + 1.f) * 127.5f, py = (z + 1.f) * 127.5f;
      px = fminf(fmaxf(px, 0.f), 255.f);
      py = fminf(fmaxf(py, 0.f), 255.f);
      int x0 = min((int)px, 254), y0 = min((int)py, 254);
      float wx = px - (float)x0, wy = py - (float)y0;
      const unsigned short* bp =
          g_feats + ((size_t)((bv * HH + y0) * WW + x0)) * CCH + cg * 8;
      ushort8 q00 = *(const ushort8*)bp;
      ushort8 q01 = *(const ushort8*)(bp + CCH);
      ushort8 q10 = *(const ushort8*)(bp + WW * CCH);
      ushort8 q11 = *(const ushort8*)(bp + WW * CCH + CCH);
      float w00 = (1.f - wx) * (1.f - wy), w01 = wx * (1.f - wy);
      float w10 = (1.f - wx) * wy, w11 = wx * wy;
      ushort8 o;
#pragma unroll
      for (int j = 0; j < 8; ++j) {
        float f = w00 * b2f(q00[j]) + w01 * b2f(q01[j]) +
                  w10 * b2f(q10[j]) + w11 * b2f(q11[j]);
        o[j] = f2b(f);
      }
      *(ushort8*)&X[v * PTS + p][cg * 8] = o;
    }
  }
  __syncthreads();

  float racc[16];
#pragma unroll
  for (int i = 0; i < 16; ++i) racc[i] = 0.f;

  // Explicit software pipeline: wload(L+1) issues right after the previous
  // barrier and overlaps layer L's MFMA. By-value WReg, no pointers -> no spill.
  WReg wA = wload(vw1_t, vb1, lane, ftBase);                       // L1
  mlp_first(&X[0][0], 168, w_in_t, vb_in, &Hb[0][0], 136, lane, ftBase);  // L0
  WReg wB = wload(vw2_t, vb2, lane, ftBase);                       // L2
  mlp_c<0, 8>(&Hb[0][0], 136, wA, nullptr, 0, &X[0][0], 168, nullptr,
              lane, ftBase);                                        // L1
  wA = wload(vw1_t + 16384, vb1 + 128, lane, ftBase);              // L3
  mlp_c<1, 8>(&X[0][0], 168, wB, &Hb[0][0], 136, &Hb[0][0], 136, nullptr,
              lane, ftBase);                                        // L2
  wB = wload(vw2_t + 16384, vb2 + 128, lane, ftBase);              // L4
  mlp_c<0, 8>(&Hb[0][0], 136, wA, nullptr, 0, &X[0][0], 168, nullptr,
              lane, ftBase);                                        // L3
  wA = wload(vw1_t + 32768, vb1 + 256, lane, ftBase);              // L5
  mlp_c<1, 8>(&X[0][0], 168, wB, &Hb[0][0], 136, &Hb[0][0], 136, nullptr,
              lane, ftBase);                                        // L4
  wB = wload(vw2_t + 32768, vb2 + 256, lane, ftBase);              // L6
  mlp_c<0, 8>(&Hb[0][0], 136, wA, nullptr, 0, &X[0][0], 168, nullptr,
              lane, ftBase);                                        // L5
  wA = wload(vw_out_t, vb_out, lane, ftBase);                      // L7
  mlp_c<1, 8>(&X[0][0], 168, wB, &Hb[0][0], 136, &Hb[0][0], 136, nullptr,
              lane, ftBase);                                        // L6
  wB = wload(gw_in_t, gb_in, lane, ftBase);                        // G0
  mlp_c<2, 8>(&Hb[0][0], 136, wA, nullptr, 0, nullptr, 0, racc,
              lane, ftBase);                                        // L7 acc

  // mean over views -> X rows 0..31 cols 0..127 (row = ph*16+col)
#pragma unroll
  for (int ph = 0; ph < 2; ++ph)
#pragma unroll
    for (int ftl = 0; ftl < 2; ++ftl) {
      u16x4 o;
#pragma unroll
      for (int r = 0; r < 4; ++r)
        o[r] = f2b(racc[ph * 8 + ftl * 4 + r] * 0.25f);
      *(u16x4*)(&X[ph * 16 + col][(ftBase + ftl) * 16 + quad * 4]) = o;
    }
  __syncthreads();

  wA = wload(gw1_t, gb1, lane, ftBase);                            // G1
  mlp_c<0, 2>(&X[0][0], 168, wB, nullptr, 0, &Hb[0][0], 136, nullptr,
              lane, ftBase);                                        // G0
  wB = wload(gw2_t, gb2, lane, ftBase);                            // G2
  mlp_c<0, 2>(&Hb[0][0], 136, wA, nullptr, 0, &X[0][0], 168, nullptr,
              lane, ftBase);                                        // G1
  wA = wload(gw1_t + 16384, gb1 + 128, lane, ftBase);              // G3
  mlp_c<1, 2>(&X[0][0], 168, wB, &Hb[0][0], 136, &Hb[0][0], 136, nullptr,
              lane, ftBase);                                        // G2
  wB = wload(gw2_t + 16384, gb2 + 128, lane, ftBase);              // G4
  mlp_c<0, 2>(&Hb[0][0], 136, wA, nullptr, 0, &X[0][0], 168, nullptr,
              lane, ftBase);                                        // G3
  mlp_c<1, 2>(&X[0][0], 168, wB, &Hb[0][0], 136, &Hb[0][0], 136, nullptr,
              lane, ftBase);                                        // G4

  // out = h @ gw_out + gb_out; 32 points, 4 lanes/point, 2 waves
  if (tid < 128) {
    const int p = (tid & 15) + ((tid >> 6) << 4);  // wave0: 0..15, wave1: 16..31
    const int q4 = (tid >> 4) & 3;
    float s = 0.f;
    const unsigned short* hr = &Hb[p][q4 * 32];
    const float* wo = gw_out + q4 * 32;
#pragma unroll
    for (int c = 0; c < 32; ++c)
      s += b2f(hr[c]) * wo[c];
    s += __shfl_xor(s, 16, 64);
    s += __shfl_xor(s, 32, 64);
    if (q4 == 0)
      out[(size_t)b * NPTSC + pts0 + p] = s + gb_out[0];
  }
}

extern "C" void kernel_launch(void* const* d_in, const int* in_sizes, int n_in,
                              void* d_out, int out_size, void* d_ws, size_t ws_size,
                              hipStream_t stream) {
  const float* views  = (const float*)d_in[0];
  const float* angles = (const float*)d_in[1];
  const int*   idx    = (const int*)d_in[2];
  const float* conv_w = (const float*)d_in[3];
  const float* conv_b = (const float*)d_in[4];
  const float* vw_in  = (const float*)d_in[5];
  const float* vb_in  = (const float*)d_in[6];
  const float* vw1    = (const float*)d_in[7];
  const float* vb1    = (const float*)d_in[8];
  const float* vw2    = (const float*)d_in[9];
  const float* vb2    = (const float*)d_in[10];
  const float* vw_out = (const float*)d_in[11];
  const float* vb_out = (const float*)d_in[12];
  const float* gw_in  = (const float*)d_in[13];
  const float* gb_in  = (const float*)d_in[14];
  const float* gw1    = (const float*)d_in[15];
  const float* gb1    = (const float*)d_in[16];
  const float* gw2    = (const float*)d_in[17];
  const float* gb2    = (const float*)d_in[18];
  const float* gw_out = (const float*)d_in[19];
  const float* gb_out = (const float*)d_in[20];

  unsigned short* wbuf = (unsigned short*)d_ws;  // 434 KB

  // fused prep+conv: 2048 conv blocks + 848 prep blocks
  hipLaunchKernelGGL(mvct_pc, dim3(2896), dim3(256), 0, stream,
                     views, conv_w, conv_b,
                     vw_in, vw1, vw2, vw_out, gw_in, gw1, gw2, wbuf);
  hipLaunchKernelGGL(mvct_main, dim3(BB * (NPTSC / PTS)), dim3(256), 0, stream,
                     angles, idx, wbuf, vb_in, vb1, vb2, vb_out,
                     gb_in, gb1, gb2, gw_out, gb_out,
                     (float*)d_out);
}